// Round 1
// baseline (197.331 us; speedup 1.0000x reference)
//
#include <hip/hip_runtime.h>
#include <hip/hip_bf16.h>
#include <math.h>

#define NN 8192      // nodes
#define FH 128       // hidden
#define NC 16        // clusters

// ---------------- workspace layout (floats) ----------------
// cnt   [8192]    in-degree counts (float, exact)
// agg4  [32768]   4-dim aggregated features
// oraw  [2048]    s^T h   (16x128)
// oadj  [256]     s^T A s (16x16)
// ssb   [256]     s^T s   (16x16)
// cab   [16]      sum_n s[n,c]*deg[n]
// csb   [16]      sum_n s[n,c]
// total accumulators = 43552 floats (zeroed each call)
// h     [1048576] hidden features (fully overwritten)
#define WS_CNT   0
#define WS_AGG4  8192
#define WS_ORAW  40960
#define WS_OADJ  43008
#define WS_SS    43264
#define WS_CA    43520
#define WS_CS    43536
#define WS_ACC_FLOATS 43552
#define WS_H     43552

// ---------------- K1: in-degree counts ----------------
__global__ void k_degree(const int* __restrict__ ei, float* __restrict__ cnt, int E) {
    int e = blockIdx.x * blockDim.x + threadIdx.x;
    if (e < E) atomicAdd(&cnt[ei[E + e]], 1.0f);   // dst row of edge_index
}

// ---------------- K2: edge aggregation in 4-dim input space ----------------
__global__ void k_edge_agg(const int* __restrict__ ei, const float* __restrict__ x,
                           const float* __restrict__ cnt, float* __restrict__ agg4, int E) {
    int e = blockIdx.x * blockDim.x + threadIdx.x;
    if (e >= E) return;
    int s = ei[e], d = ei[E + e];
    float norm = rsqrtf(cnt[s] + 1.0f) * rsqrtf(cnt[d] + 1.0f);
    float4 xv = reinterpret_cast<const float4*>(x)[s];
    atomicAdd(&agg4[d * 4 + 0], norm * xv.x);
    atomicAdd(&agg4[d * 4 + 1], norm * xv.y);
    atomicAdd(&agg4[d * 4 + 2], norm * xv.z);
    atomicAdd(&agg4[d * 4 + 3], norm * xv.w);
}

// ---------------- K3: h = relu((agg4 + x*dinv^2) @ W1 + b1) ----------------
__global__ void k_hidden(const float* __restrict__ x, const float* __restrict__ agg4,
                         const float* __restrict__ cnt, const float* __restrict__ W1,
                         const float* __restrict__ b1, float* __restrict__ h) {
    int gid = blockIdx.x * blockDim.x + threadIdx.x;   // NN*FH threads
    int n = gid >> 7, f = gid & 127;
    float dinv2 = 1.0f / (cnt[n] + 1.0f);
    float4 a  = reinterpret_cast<const float4*>(agg4)[n];
    float4 xv = reinterpret_cast<const float4*>(x)[n];
    float v = b1[f];
    v = fmaf(a.x + xv.x * dinv2, W1[0 * FH + f], v);
    v = fmaf(a.y + xv.y * dinv2, W1[1 * FH + f], v);
    v = fmaf(a.z + xv.z * dinv2, W1[2 * FH + f], v);
    v = fmaf(a.w + xv.w * dinv2, W1[3 * FH + f], v);
    h[gid] = fmaxf(v, 0.0f);
}

// ---------------- K4: s = softmax(h @ Wp + bp), 16 lanes per node ----------------
__global__ void k_assign(const float* __restrict__ h, const float* __restrict__ Wp,
                         const float* __restrict__ bp, float* __restrict__ s_out) {
    int g = threadIdx.x >> 4;    // group in block (16 groups)
    int c = threadIdx.x & 15;
    int stride = gridDim.x * 16;
    for (int n = blockIdx.x * 16 + g; n < NN; n += stride) {
        const float* hr = h + n * FH;
        float logit = bp[c];
        #pragma unroll 8
        for (int f = 0; f < FH; ++f)
            logit = fmaf(hr[f], Wp[f * NC + c], logit);
        float m = logit;
        #pragma unroll
        for (int o = 8; o; o >>= 1) m = fmaxf(m, __shfl_xor(m, o, 16));
        float ex = expf(logit - m);
        float sum = ex;
        #pragma unroll
        for (int o = 8; o; o >>= 1) sum += __shfl_xor(sum, o, 16);
        s_out[n * NC + c] = ex / sum;
    }
}

// ---------------- K5: out_raw = s^T h, ss = s^T s, ca, cluster_size ----------------
#define K5_NODES 32
__global__ void k_pool(const float* __restrict__ h, const float* __restrict__ s,
                       const float* __restrict__ cnt, float* __restrict__ oraw,
                       float* __restrict__ ssb, float* __restrict__ cab,
                       float* __restrict__ csb) {
    __shared__ float sl[K5_NODES * NC];
    __shared__ float cl[K5_NODES];
    int t = threadIdx.x;                 // 256 threads
    int f = t & 127, ch = t >> 7;        // out_raw mapping: c in [ch*8, ch*8+8)
    int cS = t >> 4, kS = t & 15;        // ss mapping
    float acc[8] = {0,0,0,0,0,0,0,0};
    float acc_ss = 0.0f, acc_ca = 0.0f, acc_cs = 0.0f;
    for (int base = blockIdx.x * K5_NODES; base < NN; base += gridDim.x * K5_NODES) {
        __syncthreads();
        sl[t]       = s[base * NC + t];
        sl[t + 256] = s[base * NC + 256 + t];
        if (t < K5_NODES) cl[t] = cnt[base + t];
        __syncthreads();
        for (int i = 0; i < K5_NODES; ++i) {
            float hv = h[(base + i) * FH + f];
            const float* sv = &sl[i * NC];
            #pragma unroll
            for (int j = 0; j < 8; ++j)
                acc[j] = fmaf(sv[ch * 8 + j], hv, acc[j]);
            acc_ss = fmaf(sv[cS], sv[kS], acc_ss);
            if (t < NC) {
                acc_ca = fmaf(sv[t], cl[i], acc_ca);
                acc_cs += sv[t];
            }
        }
    }
    #pragma unroll
    for (int j = 0; j < 8; ++j)
        atomicAdd(&oraw[(ch * 8 + j) * FH + f], acc[j]);
    atomicAdd(&ssb[cS * NC + kS], acc_ss);
    if (t < NC) {
        atomicAdd(&cab[t], acc_ca);
        atomicAdd(&csb[t], acc_cs);
    }
}

// ---------------- K6: out_adj[k][c] = sum_e s[src,k]*s[dst,c] ----------------
__global__ void k_edge_adj(const int* __restrict__ ei, const float* __restrict__ s,
                           float* __restrict__ oadj, int E) {
    int t = threadIdx.x;
    int c = t & 15;
    int grp  = (blockIdx.x * blockDim.x + t) >> 4;
    int ngrp = (gridDim.x * blockDim.x) >> 4;
    float acc[16];
    #pragma unroll
    for (int k = 0; k < 16; ++k) acc[k] = 0.0f;
    for (int e = grp; e < E; e += ngrp) {
        int sN = ei[e], dN = ei[E + e];
        float a = s[sN * NC + c];   // s_src[c]
        float b = s[dN * NC + c];   // s_dst[c]
        #pragma unroll
        for (int k = 0; k < 16; ++k)
            acc[k] = fmaf(__shfl(a, k, 16), b, acc[k]);   // += s_src[k]*s_dst[c]
    }
    __shared__ float red[16 * 16 * 16];   // [group][k][c]
    int gl = t >> 4;
    #pragma unroll
    for (int k = 0; k < 16; ++k) red[gl * 256 + k * 16 + c] = acc[k];
    __syncthreads();
    int kk = t >> 4, cc = t & 15;
    float v = 0.0f;
    #pragma unroll
    for (int g = 0; g < 16; ++g) v += red[g * 256 + kk * 16 + cc];
    atomicAdd(&oadj[kk * 16 + cc], v);
}

// ---------------- K7: losses + selu + log_softmax (single block, 128 thr) ----------------
__device__ __forceinline__ float bsum(float v) {
    __shared__ float sh[2];
    #pragma unroll
    for (int o = 32; o; o >>= 1) v += __shfl_down(v, o, 64);
    if ((threadIdx.x & 63) == 0) sh[threadIdx.x >> 6] = v;
    __syncthreads();
    float r = sh[0] + sh[1];
    __syncthreads();
    return r;
}
__device__ __forceinline__ float bmax(float v) {
    __shared__ float sh[2];
    #pragma unroll
    for (int o = 32; o; o >>= 1) v = fmaxf(v, __shfl_down(v, o, 64));
    if ((threadIdx.x & 63) == 0) sh[threadIdx.x >> 6] = v;
    __syncthreads();
    float r = fmaxf(sh[0], sh[1]);
    __syncthreads();
    return r;
}
__device__ __forceinline__ float selu_f(float x) {
    const float a = 1.6732632423543772f, sc = 1.0507009873554805f;
    return sc * (x > 0.0f ? x : a * (expf(x) - 1.0f));
}

__global__ void k_final(const float* __restrict__ oraw, const float* __restrict__ oadj,
                        const float* __restrict__ ssb, const float* __restrict__ cab,
                        const float* __restrict__ csb, float* __restrict__ d_out,
                        float Ef) {
    int t = threadIdx.x;   // 128 threads
    // orthogonality loss
    float s0 = ssb[t], s1 = ssb[t + 128];
    float fro = sqrtf(bsum(s0 * s0 + s1 * s1));
    float d0 = s0 / fro - ((t % 17 == 0) ? 0.25f : 0.0f);
    float d1 = s1 / fro - (((t + 128) % 17 == 0) ? 0.25f : 0.0f);
    float ortho = sqrtf(bsum(d0 * d0 + d1 * d1));
    // spectral loss: -(tr(out_adj) - sum(ca^2)/E) / E     (2m == E)
    float tv  = (t < NC) ? oadj[t * 17] : 0.0f;
    float tr_adj = bsum(tv);
    float cav = (t < NC) ? cab[t] * cab[t] : 0.0f;
    float tr_n = bsum(cav) / Ef;
    float spectral = -(tr_adj - tr_n) / Ef;
    // cluster loss
    float csv = (t < NC) ? csb[t] * csb[t] : 0.0f;
    float cluster = sqrtf(bsum(csv)) / (float)NN * 4.0f - 1.0f;
    if (t == 0) d_out[NC * FH] = spectral + ortho + cluster;
    // log_softmax(selu(out_raw)) rows
    for (int cR = 0; cR < NC; ++cR) {
        float v = selu_f(oraw[cR * FH + t]);
        float mx = bmax(v);
        float e = expf(v - mx);
        float sm = bsum(e);
        d_out[cR * FH + t] = v - mx - logf(sm);
    }
}

extern "C" void kernel_launch(void* const* d_in, const int* in_sizes, int n_in,
                              void* d_out, int out_size, void* d_ws, size_t ws_size,
                              hipStream_t stream) {
    const float* x  = (const float*)d_in[0];
    const float* W1 = (const float*)d_in[1];
    const float* b1 = (const float*)d_in[2];
    const float* Wp = (const float*)d_in[3];
    const float* bp = (const float*)d_in[4];
    const int*   ei = (const int*)d_in[5];
    int E = in_sizes[5] / 2;

    float* ws   = (float*)d_ws;
    float* cnt  = ws + WS_CNT;
    float* agg4 = ws + WS_AGG4;
    float* oraw = ws + WS_ORAW;
    float* oadj = ws + WS_OADJ;
    float* ssb  = ws + WS_SS;
    float* cab  = ws + WS_CA;
    float* csb  = ws + WS_CS;
    float* h    = ws + WS_H;

    float* out  = (float*)d_out;          // [0..2047] log_softmax, [2048] loss
    float* s    = out + NC * FH + 1;      // [2049 ..] assignments (8192 x 16)

    hipMemsetAsync(d_ws, 0, WS_ACC_FLOATS * sizeof(float), stream);

    k_degree  <<<(E + 255) / 256, 256, 0, stream>>>(ei, cnt, E);
    k_edge_agg<<<(E + 255) / 256, 256, 0, stream>>>(ei, x, cnt, agg4, E);
    k_hidden  <<<(NN * FH) / 256, 256, 0, stream>>>(x, agg4, cnt, W1, b1, h);
    k_assign  <<<64, 256, 0, stream>>>(h, Wp, bp, s);
    k_pool    <<<64, 256, 0, stream>>>(h, s, cnt, oraw, ssb, cab, csb);
    k_edge_adj<<<128, 256, 0, stream>>>(ei, s, oadj, E);
    k_final   <<<1, 128, 0, stream>>>(oraw, oadj, ssb, cab, csb, out, (float)E);
}

// Round 2
// 90.324 us; speedup vs baseline: 2.1847x; 2.1847x over previous
//
#include <hip/hip_runtime.h>
#include <hip/hip_bf16.h>
#include <math.h>

#define NN 8192      // nodes
#define FH 128       // hidden
#define NC 16        // clusters
#define HP 132       // padded LDS row (16B aligned, bank-rotating)

// ---------------- workspace layout (floats) ----------------
#define WS_CNT   0          // [8192]
#define WS_AGG4  8192       // [32768]
#define WS_ORAW  40960      // 4 x 2048 replicas
#define WS_SS    49152      // 4 x 256
#define WS_CA    50176      // 16 x 16
#define WS_CS    50432      // 16 x 16
#define WS_OADJ  50688      // 4 x 256
#define WS_ACC_FLOATS 51712

// ---------------- K1: in-degree counts ----------------
__global__ __launch_bounds__(256) void k_degree(const int* __restrict__ ei,
                                                float* __restrict__ cnt, int E) {
    int e = blockIdx.x * blockDim.x + threadIdx.x;
    if (e < E) atomicAdd(&cnt[ei[E + e]], 1.0f);
}

// ---------------- K2: edge aggregation in 4-dim input space ----------------
__global__ __launch_bounds__(256) void k_edge_agg(const int* __restrict__ ei,
                                                  const float* __restrict__ x,
                                                  const float* __restrict__ cnt,
                                                  float* __restrict__ agg4, int E) {
    int e = blockIdx.x * blockDim.x + threadIdx.x;
    if (e >= E) return;
    int s = ei[e], d = ei[E + e];
    float norm = rsqrtf(cnt[s] + 1.0f) * rsqrtf(cnt[d] + 1.0f);
    float4 xv = reinterpret_cast<const float4*>(x)[s];
    atomicAdd(&agg4[d * 4 + 0], norm * xv.x);
    atomicAdd(&agg4[d * 4 + 1], norm * xv.y);
    atomicAdd(&agg4[d * 4 + 2], norm * xv.z);
    atomicAdd(&agg4[d * 4 + 3], norm * xv.w);
}

// ---------------- K3: fused node pipeline ----------------
// 256 blocks x 256 threads, 32 nodes per block.
// z -> h (LDS) -> s (softmax, write to d_out) -> pooled partials via atomics.
#define CHUNK 32
__global__ __launch_bounds__(256) void k_node(const float* __restrict__ x,
                                              const float* __restrict__ agg4,
                                              const float* __restrict__ cnt,
                                              const float* __restrict__ W1,
                                              const float* __restrict__ b1,
                                              const float* __restrict__ Wp,
                                              const float* __restrict__ bp,
                                              float* __restrict__ s_out,
                                              float* __restrict__ oraw,
                                              float* __restrict__ ssb,
                                              float* __restrict__ cab,
                                              float* __restrict__ csb) {
    __shared__ float h_lds[CHUNK][HP];     // ~16.9 KB
    __shared__ float wpT[NC * HP];         // ~8.4 KB, Wp transposed [c][f]
    __shared__ float s_lds[CHUNK][NC];     // 2 KB
    __shared__ float z_lds[CHUNK][4];
    __shared__ float c_lds[CHUNK];
    int t = threadIdx.x;
    int base = blockIdx.x * CHUNK;

    // stage Wp transposed
    #pragma unroll
    for (int r = 0; r < 8; ++r) {
        int idx = r * 256 + t;             // = f*16 + c
        wpT[(idx & 15) * HP + (idx >> 4)] = Wp[idx];
    }
    // z = agg4 + x * dinv^2
    if (t < CHUNK) {
        float4 a  = reinterpret_cast<const float4*>(agg4)[base + t];
        float4 xv = reinterpret_cast<const float4*>(x)[base + t];
        float cn = cnt[base + t];
        c_lds[t] = cn;
        float di = 1.0f / (cn + 1.0f);
        z_lds[t][0] = a.x + xv.x * di;
        z_lds[t][1] = a.y + xv.y * di;
        z_lds[t][2] = a.z + xv.z * di;
        z_lds[t][3] = a.w + xv.w * di;
    }
    __syncthreads();

    // h = relu(z @ W1 + b1) into LDS
    int f = t & 127;
    {
        float w0 = W1[f], w1 = W1[128 + f], w2 = W1[256 + f], w3 = W1[384 + f];
        float bb = b1[f];
        int n0 = t >> 7;                   // 0 or 1
        #pragma unroll
        for (int r = 0; r < 16; ++r) {
            int n = n0 + r * 2;
            float v = fmaf(z_lds[n][0], w0, bb);
            v = fmaf(z_lds[n][1], w1, v);
            v = fmaf(z_lds[n][2], w2, v);
            v = fmaf(z_lds[n][3], w3, v);
            h_lds[n][f] = fmaxf(v, 0.0f);
        }
    }
    __syncthreads();

    // s = softmax(h @ Wp + bp): 16 lanes per node, 2 passes
    int c = t & 15, g = t >> 4;
    const float4* wrow = reinterpret_cast<const float4*>(&wpT[c * HP]);
    #pragma unroll
    for (int pass = 0; pass < 2; ++pass) {
        int n = pass * 16 + g;
        const float4* hrow = reinterpret_cast<const float4*>(&h_lds[n][0]);
        float logit = bp[c];
        #pragma unroll 8
        for (int q = 0; q < 32; ++q) {
            float4 hv = hrow[q];
            float4 wv = wrow[q];
            logit = fmaf(hv.x, wv.x, logit);
            logit = fmaf(hv.y, wv.y, logit);
            logit = fmaf(hv.z, wv.z, logit);
            logit = fmaf(hv.w, wv.w, logit);
        }
        float m = logit;
        #pragma unroll
        for (int o = 8; o; o >>= 1) m = fmaxf(m, __shfl_xor(m, o, 16));
        float ex = expf(logit - m);
        float sum = ex;
        #pragma unroll
        for (int o = 8; o; o >>= 1) sum += __shfl_xor(sum, o, 16);
        float sv = ex / sum;
        s_lds[n][c] = sv;
        s_out[(base + n) * NC + c] = sv;
    }
    __syncthreads();

    // pooled partials: oraw = s^T h, ss = s^T s, ca, cs
    float acc[8] = {0, 0, 0, 0, 0, 0, 0, 0};
    float acc_ss = 0.0f, acc_ca = 0.0f, acc_cs = 0.0f;
    int ch = t >> 7;
    int cS = t >> 4, kS = t & 15;
    #pragma unroll
    for (int i = 0; i < CHUNK; ++i) {
        float hv = h_lds[i][f];
        const float4* sv = reinterpret_cast<const float4*>(&s_lds[i][0]);
        float4 sa = sv[ch * 2], sb = sv[ch * 2 + 1];
        acc[0] = fmaf(sa.x, hv, acc[0]);
        acc[1] = fmaf(sa.y, hv, acc[1]);
        acc[2] = fmaf(sa.z, hv, acc[2]);
        acc[3] = fmaf(sa.w, hv, acc[3]);
        acc[4] = fmaf(sb.x, hv, acc[4]);
        acc[5] = fmaf(sb.y, hv, acc[5]);
        acc[6] = fmaf(sb.z, hv, acc[6]);
        acc[7] = fmaf(sb.w, hv, acc[7]);
        acc_ss = fmaf(s_lds[i][cS], s_lds[i][kS], acc_ss);
    }
    if (t < NC) {
        #pragma unroll
        for (int i = 0; i < CHUNK; ++i) {
            acc_ca = fmaf(s_lds[i][t], c_lds[i], acc_ca);
            acc_cs += s_lds[i][t];
        }
    }
    int rep = blockIdx.x & 3;
    #pragma unroll
    for (int j = 0; j < 8; ++j)
        atomicAdd(&oraw[rep * 2048 + (ch * 8 + j) * FH + f], acc[j]);
    atomicAdd(&ssb[rep * 256 + cS * NC + kS], acc_ss);
    if (t < NC) {
        int rep16 = blockIdx.x & 15;
        atomicAdd(&cab[rep16 * NC + t], acc_ca);
        atomicAdd(&csb[rep16 * NC + t], acc_cs);
    }
}

// ---------------- K4: out_adj[k][c] = sum_e s[src,k]*s[dst,c] ----------------
__global__ __launch_bounds__(256) void k_edge_adj(const int* __restrict__ ei,
                                                  const float* __restrict__ s,
                                                  float* __restrict__ oadj, int E) {
    int t = threadIdx.x;
    int c = t & 15;
    int grp  = (blockIdx.x * blockDim.x + t) >> 4;
    int ngrp = (gridDim.x * blockDim.x) >> 4;
    float acc[16];
    #pragma unroll
    for (int k = 0; k < 16; ++k) acc[k] = 0.0f;
    for (int e = grp; e < E; e += ngrp) {
        int sN = ei[e], dN = ei[E + e];
        float a = s[sN * NC + c];
        float b = s[dN * NC + c];
        #pragma unroll
        for (int k = 0; k < 16; ++k)
            acc[k] = fmaf(__shfl(a, k, 16), b, acc[k]);
    }
    __shared__ float red[16 * 16 * 16];
    int gl = t >> 4;
    #pragma unroll
    for (int k = 0; k < 16; ++k) red[gl * 256 + k * 16 + c] = acc[k];
    __syncthreads();
    int kk = t >> 4, cc = t & 15;
    float v = 0.0f;
    #pragma unroll
    for (int g2 = 0; g2 < 16; ++g2) v += red[g2 * 256 + kk * 16 + cc];
    atomicAdd(&oadj[(blockIdx.x & 3) * 256 + kk * 16 + cc], v);
}

// ---------------- K5: losses + selu + log_softmax ----------------
__device__ __forceinline__ float bsum(float v) {
    __shared__ float sh[2];
    #pragma unroll
    for (int o = 32; o; o >>= 1) v += __shfl_down(v, o, 64);
    if ((threadIdx.x & 63) == 0) sh[threadIdx.x >> 6] = v;
    __syncthreads();
    float r = sh[0] + sh[1];
    __syncthreads();
    return r;
}
__device__ __forceinline__ float bmax(float v) {
    __shared__ float sh[2];
    #pragma unroll
    for (int o = 32; o; o >>= 1) v = fmaxf(v, __shfl_down(v, o, 64));
    if ((threadIdx.x & 63) == 0) sh[threadIdx.x >> 6] = v;
    __syncthreads();
    float r = fmaxf(sh[0], sh[1]);
    __syncthreads();
    return r;
}
__device__ __forceinline__ float selu_f(float x) {
    const float a = 1.6732632423543772f, sc = 1.0507009873554805f;
    return sc * (x > 0.0f ? x : a * (expf(x) - 1.0f));
}

__global__ __launch_bounds__(128) void k_final(const float* __restrict__ oraw,
                                               const float* __restrict__ oadj,
                                               const float* __restrict__ ssb,
                                               const float* __restrict__ cab,
                                               const float* __restrict__ csb,
                                               float* __restrict__ d_out, float Ef) {
    int t = threadIdx.x;   // 128 threads
    // reduce ss replicas
    float s0 = 0.0f, s1 = 0.0f;
    #pragma unroll
    for (int r = 0; r < 4; ++r) { s0 += ssb[r * 256 + t]; s1 += ssb[r * 256 + 128 + t]; }
    float fro = sqrtf(bsum(s0 * s0 + s1 * s1));
    float d0 = s0 / fro - ((t % 17 == 0) ? 0.25f : 0.0f);
    float d1 = s1 / fro - (((t + 128) % 17 == 0) ? 0.25f : 0.0f);
    float ortho = sqrtf(bsum(d0 * d0 + d1 * d1));
    // spectral
    float tv = 0.0f, ca = 0.0f, cs = 0.0f;
    if (t < NC) {
        #pragma unroll
        for (int r = 0; r < 4; ++r) tv += oadj[r * 256 + t * 17];
        #pragma unroll
        for (int r = 0; r < 16; ++r) { ca += cab[r * NC + t]; cs += csb[r * NC + t]; }
    }
    float tr_adj = bsum(tv);
    float tr_n = bsum(ca * ca) / Ef;
    float spectral = -(tr_adj - tr_n) / Ef;
    // cluster
    float cluster = sqrtf(bsum(cs * cs)) / (float)NN * 4.0f - 1.0f;
    if (t == 0) d_out[NC * FH] = spectral + ortho + cluster;
    // log_softmax(selu(out_raw))
    for (int cR = 0; cR < NC; ++cR) {
        float v = 0.0f;
        #pragma unroll
        for (int r = 0; r < 4; ++r) v += oraw[r * 2048 + cR * FH + t];
        v = selu_f(v);
        float mx = bmax(v);
        float e = expf(v - mx);
        float sm = bsum(e);
        d_out[cR * FH + t] = v - mx - logf(sm);
    }
}

extern "C" void kernel_launch(void* const* d_in, const int* in_sizes, int n_in,
                              void* d_out, int out_size, void* d_ws, size_t ws_size,
                              hipStream_t stream) {
    const float* x  = (const float*)d_in[0];
    const float* W1 = (const float*)d_in[1];
    const float* b1 = (const float*)d_in[2];
    const float* Wp = (const float*)d_in[3];
    const float* bp = (const float*)d_in[4];
    const int*   ei = (const int*)d_in[5];
    int E = in_sizes[5] / 2;

    float* ws   = (float*)d_ws;
    float* cnt  = ws + WS_CNT;
    float* agg4 = ws + WS_AGG4;
    float* oraw = ws + WS_ORAW;
    float* ssb  = ws + WS_SS;
    float* cab  = ws + WS_CA;
    float* csb  = ws + WS_CS;
    float* oadj = ws + WS_OADJ;

    float* out  = (float*)d_out;          // [0..2047] log_softmax, [2048] loss
    float* s    = out + NC * FH + 1;      // [2049..] assignments (8192 x 16)

    hipMemsetAsync(d_ws, 0, WS_ACC_FLOATS * sizeof(float), stream);

    k_degree  <<<(E + 255) / 256, 256, 0, stream>>>(ei, cnt, E);
    k_edge_agg<<<(E + 255) / 256, 256, 0, stream>>>(ei, x, cnt, agg4, E);
    k_node    <<<NN / CHUNK, 256, 0, stream>>>(x, agg4, cnt, W1, b1, Wp, bp,
                                               s, oraw, ssb, cab, csb);
    k_edge_adj<<<256, 256, 0, stream>>>(ei, s, oadj, E);
    k_final   <<<1, 128, 0, stream>>>(oraw, oadj, ssb, cab, csb, out, (float)E);
}

// Round 3
// 89.784 us; speedup vs baseline: 2.1978x; 1.0060x over previous
//
#include <hip/hip_runtime.h>
#include <hip/hip_bf16.h>
#include <math.h>

#define NN 8192      // nodes
#define FH 128       // hidden
#define NC 16        // clusters
#define HP 132       // padded LDS row (16B aligned, bank-rotating)

// ---------------- workspace layout (floats) ----------------
#define WS_CNT   0          // [8192]
#define WS_AGG4  8192       // [32768]
#define WS_ORAW  40960      // 4 x 2048 replicas
#define WS_SS    49152      // 4 x 256
#define WS_CA    50176      // 16 x 16
#define WS_CS    50432      // 16 x 16
#define WS_OADJ  50688      // 4 x 256
#define WS_ACC_FLOATS 51712

// ---------------- K0: zero accumulators (replaces 39us fillBuffer) ----------------
__global__ __launch_bounds__(256) void k_zero(float4* __restrict__ ws) {
    int i = blockIdx.x * blockDim.x + threadIdx.x;
    if (i < WS_ACC_FLOATS / 4) ws[i] = make_float4(0.f, 0.f, 0.f, 0.f);
}

// ---------------- K1: in-degree counts ----------------
__global__ __launch_bounds__(256) void k_degree(const int* __restrict__ ei,
                                                float* __restrict__ cnt, int E) {
    int e = blockIdx.x * blockDim.x + threadIdx.x;
    if (e < E) atomicAdd(&cnt[ei[E + e]], 1.0f);
}

// ---------------- K2: edge aggregation in 4-dim input space ----------------
__global__ __launch_bounds__(256) void k_edge_agg(const int* __restrict__ ei,
                                                  const float* __restrict__ x,
                                                  const float* __restrict__ cnt,
                                                  float* __restrict__ agg4, int E) {
    int e = blockIdx.x * blockDim.x + threadIdx.x;
    if (e >= E) return;
    int s = ei[e], d = ei[E + e];
    float norm = rsqrtf(cnt[s] + 1.0f) * rsqrtf(cnt[d] + 1.0f);
    float4 xv = reinterpret_cast<const float4*>(x)[s];
    atomicAdd(&agg4[d * 4 + 0], norm * xv.x);
    atomicAdd(&agg4[d * 4 + 1], norm * xv.y);
    atomicAdd(&agg4[d * 4 + 2], norm * xv.z);
    atomicAdd(&agg4[d * 4 + 3], norm * xv.w);
}

// ---------------- K3: fused node pipeline ----------------
// 256 blocks x 256 threads, 32 nodes per block.
// z -> h (LDS) -> s (softmax, write to d_out) -> pooled partials via atomics.
#define CHUNK 32
__global__ __launch_bounds__(256) void k_node(const float* __restrict__ x,
                                              const float* __restrict__ agg4,
                                              const float* __restrict__ cnt,
                                              const float* __restrict__ W1,
                                              const float* __restrict__ b1,
                                              const float* __restrict__ Wp,
                                              const float* __restrict__ bp,
                                              float* __restrict__ s_out,
                                              float* __restrict__ oraw,
                                              float* __restrict__ ssb,
                                              float* __restrict__ cab,
                                              float* __restrict__ csb) {
    __shared__ float h_lds[CHUNK][HP];     // ~16.9 KB
    __shared__ float wpT[NC * HP];         // ~8.4 KB, Wp transposed [c][f]
    __shared__ float s_lds[CHUNK][NC];     // 2 KB
    __shared__ float z_lds[CHUNK][4];
    __shared__ float c_lds[CHUNK];
    int t = threadIdx.x;
    int base = blockIdx.x * CHUNK;

    // stage Wp transposed
    #pragma unroll
    for (int r = 0; r < 8; ++r) {
        int idx = r * 256 + t;             // = f*16 + c
        wpT[(idx & 15) * HP + (idx >> 4)] = Wp[idx];
    }
    // z = agg4 + x * dinv^2
    if (t < CHUNK) {
        float4 a  = reinterpret_cast<const float4*>(agg4)[base + t];
        float4 xv = reinterpret_cast<const float4*>(x)[base + t];
        float cn = cnt[base + t];
        c_lds[t] = cn;
        float di = 1.0f / (cn + 1.0f);
        z_lds[t][0] = a.x + xv.x * di;
        z_lds[t][1] = a.y + xv.y * di;
        z_lds[t][2] = a.z + xv.z * di;
        z_lds[t][3] = a.w + xv.w * di;
    }
    __syncthreads();

    // h = relu(z @ W1 + b1) into LDS
    int f = t & 127;
    {
        float w0 = W1[f], w1 = W1[128 + f], w2 = W1[256 + f], w3 = W1[384 + f];
        float bb = b1[f];
        int n0 = t >> 7;                   // 0 or 1
        #pragma unroll
        for (int r = 0; r < 16; ++r) {
            int n = n0 + r * 2;
            float v = fmaf(z_lds[n][0], w0, bb);
            v = fmaf(z_lds[n][1], w1, v);
            v = fmaf(z_lds[n][2], w2, v);
            v = fmaf(z_lds[n][3], w3, v);
            h_lds[n][f] = fmaxf(v, 0.0f);
        }
    }
    __syncthreads();

    // s = softmax(h @ Wp + bp): 16 lanes per node, 2 passes
    int c = t & 15, g = t >> 4;
    const float4* wrow = reinterpret_cast<const float4*>(&wpT[c * HP]);
    #pragma unroll
    for (int pass = 0; pass < 2; ++pass) {
        int n = pass * 16 + g;
        const float4* hrow = reinterpret_cast<const float4*>(&h_lds[n][0]);
        float logit = bp[c];
        #pragma unroll 8
        for (int q = 0; q < 32; ++q) {
            float4 hv = hrow[q];
            float4 wv = wrow[q];
            logit = fmaf(hv.x, wv.x, logit);
            logit = fmaf(hv.y, wv.y, logit);
            logit = fmaf(hv.z, wv.z, logit);
            logit = fmaf(hv.w, wv.w, logit);
        }
        float m = logit;
        #pragma unroll
        for (int o = 8; o; o >>= 1) m = fmaxf(m, __shfl_xor(m, o, 16));
        float ex = expf(logit - m);
        float sum = ex;
        #pragma unroll
        for (int o = 8; o; o >>= 1) sum += __shfl_xor(sum, o, 16);
        float sv = ex / sum;
        s_lds[n][c] = sv;
        s_out[(base + n) * NC + c] = sv;
    }
    __syncthreads();

    // pooled partials: oraw = s^T h, ss = s^T s, ca, cs
    float acc[8] = {0, 0, 0, 0, 0, 0, 0, 0};
    float acc_ss = 0.0f, acc_ca = 0.0f, acc_cs = 0.0f;
    int ch = t >> 7;
    int cS = t >> 4, kS = t & 15;
    #pragma unroll
    for (int i = 0; i < CHUNK; ++i) {
        float hv = h_lds[i][f];
        const float4* sv = reinterpret_cast<const float4*>(&s_lds[i][0]);
        float4 sa = sv[ch * 2], sb = sv[ch * 2 + 1];
        acc[0] = fmaf(sa.x, hv, acc[0]);
        acc[1] = fmaf(sa.y, hv, acc[1]);
        acc[2] = fmaf(sa.z, hv, acc[2]);
        acc[3] = fmaf(sa.w, hv, acc[3]);
        acc[4] = fmaf(sb.x, hv, acc[4]);
        acc[5] = fmaf(sb.y, hv, acc[5]);
        acc[6] = fmaf(sb.z, hv, acc[6]);
        acc[7] = fmaf(sb.w, hv, acc[7]);
        acc_ss = fmaf(s_lds[i][cS], s_lds[i][kS], acc_ss);
    }
    if (t < NC) {
        #pragma unroll
        for (int i = 0; i < CHUNK; ++i) {
            acc_ca = fmaf(s_lds[i][t], c_lds[i], acc_ca);
            acc_cs += s_lds[i][t];
        }
    }
    int rep = blockIdx.x & 3;
    #pragma unroll
    for (int j = 0; j < 8; ++j)
        atomicAdd(&oraw[rep * 2048 + (ch * 8 + j) * FH + f], acc[j]);
    atomicAdd(&ssb[rep * 256 + cS * NC + kS], acc_ss);
    if (t < NC) {
        int rep16 = blockIdx.x & 15;
        atomicAdd(&cab[rep16 * NC + t], acc_ca);
        atomicAdd(&csb[rep16 * NC + t], acc_cs);
    }
}

// ---------------- K4: out_adj[k][c] = sum_e s[src,k]*s[dst,c] ----------------
__global__ __launch_bounds__(256) void k_edge_adj(const int* __restrict__ ei,
                                                  const float* __restrict__ s,
                                                  float* __restrict__ oadj, int E) {
    int t = threadIdx.x;
    int c = t & 15;
    int grp  = (blockIdx.x * blockDim.x + t) >> 4;
    int ngrp = (gridDim.x * blockDim.x) >> 4;
    float acc[16];
    #pragma unroll
    for (int k = 0; k < 16; ++k) acc[k] = 0.0f;
    for (int e = grp; e < E; e += ngrp) {
        int sN = ei[e], dN = ei[E + e];
        float a = s[sN * NC + c];
        float b = s[dN * NC + c];
        #pragma unroll
        for (int k = 0; k < 16; ++k)
            acc[k] = fmaf(__shfl(a, k, 16), b, acc[k]);
    }
    __shared__ float red[16 * 16 * 16];
    int gl = t >> 4;
    #pragma unroll
    for (int k = 0; k < 16; ++k) red[gl * 256 + k * 16 + c] = acc[k];
    __syncthreads();
    int kk = t >> 4, cc = t & 15;
    float v = 0.0f;
    #pragma unroll
    for (int g2 = 0; g2 < 16; ++g2) v += red[g2 * 256 + kk * 16 + cc];
    atomicAdd(&oadj[(blockIdx.x & 3) * 256 + kk * 16 + cc], v);
}

// ---------------- K5: losses + selu + log_softmax ----------------
__device__ __forceinline__ float bsum(float v) {
    __shared__ float sh[2];
    #pragma unroll
    for (int o = 32; o; o >>= 1) v += __shfl_down(v, o, 64);
    if ((threadIdx.x & 63) == 0) sh[threadIdx.x >> 6] = v;
    __syncthreads();
    float r = sh[0] + sh[1];
    __syncthreads();
    return r;
}
__device__ __forceinline__ float bmax(float v) {
    __shared__ float sh[2];
    #pragma unroll
    for (int o = 32; o; o >>= 1) v = fmaxf(v, __shfl_down(v, o, 64));
    if ((threadIdx.x & 63) == 0) sh[threadIdx.x >> 6] = v;
    __syncthreads();
    float r = fmaxf(sh[0], sh[1]);
    __syncthreads();
    return r;
}
__device__ __forceinline__ float selu_f(float x) {
    const float a = 1.6732632423543772f, sc = 1.0507009873554805f;
    return sc * (x > 0.0f ? x : a * (expf(x) - 1.0f));
}

__global__ __launch_bounds__(128) void k_final(const float* __restrict__ oraw,
                                               const float* __restrict__ oadj,
                                               const float* __restrict__ ssb,
                                               const float* __restrict__ cab,
                                               const float* __restrict__ csb,
                                               float* __restrict__ d_out, float Ef) {
    int t = threadIdx.x;   // 128 threads
    // reduce ss replicas
    float s0 = 0.0f, s1 = 0.0f;
    #pragma unroll
    for (int r = 0; r < 4; ++r) { s0 += ssb[r * 256 + t]; s1 += ssb[r * 256 + 128 + t]; }
    float fro = sqrtf(bsum(s0 * s0 + s1 * s1));
    float d0 = s0 / fro - ((t % 17 == 0) ? 0.25f : 0.0f);
    float d1 = s1 / fro - (((t + 128) % 17 == 0) ? 0.25f : 0.0f);
    float ortho = sqrtf(bsum(d0 * d0 + d1 * d1));
    // spectral
    float tv = 0.0f, ca = 0.0f, cs = 0.0f;
    if (t < NC) {
        #pragma unroll
        for (int r = 0; r < 4; ++r) tv += oadj[r * 256 + t * 17];
        #pragma unroll
        for (int r = 0; r < 16; ++r) { ca += cab[r * NC + t]; cs += csb[r * NC + t]; }
    }
    float tr_adj = bsum(tv);
    float tr_n = bsum(ca * ca) / Ef;
    float spectral = -(tr_adj - tr_n) / Ef;
    // cluster
    float cluster = sqrtf(bsum(cs * cs)) / (float)NN * 4.0f - 1.0f;
    if (t == 0) d_out[NC * FH] = spectral + ortho + cluster;
    // log_softmax(selu(out_raw))
    for (int cR = 0; cR < NC; ++cR) {
        float v = 0.0f;
        #pragma unroll
        for (int r = 0; r < 4; ++r) v += oraw[r * 2048 + cR * FH + t];
        v = selu_f(v);
        float mx = bmax(v);
        float e = expf(v - mx);
        float sm = bsum(e);
        d_out[cR * FH + t] = v - mx - logf(sm);
    }
}

extern "C" void kernel_launch(void* const* d_in, const int* in_sizes, int n_in,
                              void* d_out, int out_size, void* d_ws, size_t ws_size,
                              hipStream_t stream) {
    const float* x  = (const float*)d_in[0];
    const float* W1 = (const float*)d_in[1];
    const float* b1 = (const float*)d_in[2];
    const float* Wp = (const float*)d_in[3];
    const float* bp = (const float*)d_in[4];
    const int*   ei = (const int*)d_in[5];
    int E = in_sizes[5] / 2;

    float* ws   = (float*)d_ws;
    float* cnt  = ws + WS_CNT;
    float* agg4 = ws + WS_AGG4;
    float* oraw = ws + WS_ORAW;
    float* ssb  = ws + WS_SS;
    float* cab  = ws + WS_CA;
    float* csb  = ws + WS_CS;
    float* oadj = ws + WS_OADJ;

    float* out  = (float*)d_out;          // [0..2047] log_softmax, [2048] loss
    float* s    = out + NC * FH + 1;      // [2049..] assignments (8192 x 16)

    k_zero    <<<(WS_ACC_FLOATS / 4 + 255) / 256, 256, 0, stream>>>((float4*)d_ws);
    k_degree  <<<(E + 255) / 256, 256, 0, stream>>>(ei, cnt, E);
    k_edge_agg<<<(E + 255) / 256, 256, 0, stream>>>(ei, x, cnt, agg4, E);
    k_node    <<<NN / CHUNK, 256, 0, stream>>>(x, agg4, cnt, W1, b1, Wp, bp,
                                               s, oraw, ssb, cab, csb);
    k_edge_adj<<<256, 256, 0, stream>>>(ei, s, oadj, E);
    k_final   <<<1, 128, 0, stream>>>(oraw, oadj, ssb, cab, csb, out, (float)E);
}